// Round 21
// baseline (86.468 us; speedup 1.0000x reference)
//
#include <hip/hip_runtime.h>

#define RES 128
#define NCELLS (RES * RES * RES)        // 2097152
#define CASC 4
#define GRID_TOTAL (CASC * NCELLS)      // 8388608 = 2^23
#define NBYTES (GRID_TOTAL / 8)         // 1048576
#define MAIN_BLOCKS (NCELLS / (256 * 8))     // 1024 (8 consecutive morton/thread)

typedef float f32x2 __attribute__((ext_vector_type(2)));

struct f3v { float x, y, z; };
__device__ __forceinline__ f3v load3(const float* __restrict__ p) {
    f3v v;
    __builtin_memcpy(&v, p, sizeof(f3v));   // -> global_load_dwordx3 (12B, 4B-aligned)
    return v;
}

// inverse of instant-ngp expand_bits: gather every 3rd bit
__device__ __forceinline__ unsigned compact3(unsigned v) {
    v &= 0x49249249u;
    v = (v | (v >> 2))  & 0xC30C30C3u;
    v = (v | (v >> 4))  & 0x0F00F00Fu;
    v = (v | (v >> 8))  & 0xFF0000FFu;
    v = (v | (v >> 16)) & 0x3FFu;
    return v;
}

__device__ __forceinline__ f32x2 pk_fma(f32x2 a, f32x2 b, f32x2 c) {
    return __builtin_elementwise_fma(a, b, c);   // v_pk_fma_f32, IEEE fma per lane
}

// fast softplus: hardware v_exp_f32 / v_log_f32 (~8 instrs vs libm's ~50).
__device__ __forceinline__ float fast_softplus(float a) {
    return fmaxf(a, 0.0f) + __logf(1.0f + __expf(-fabsf(a)));
}

// 1024 blocks x 256 threads; thread handles morton m = tid8*8 + {0..7} as two
// float4-groups (G = 0,1). 2x per-thread memory-level parallelism vs R20;
// per-cell arithmetic byte-identical.
__global__ __launch_bounds__(256) void dg_main(
    const float* __restrict__ dgrid,   // [CASC, NCELLS]
    const float* __restrict__ jit,     // [CASC, NCELLS, 3]
    const float* __restrict__ W1,      // [3,32]
    const float* __restrict__ b1,      // [32]
    const float* __restrict__ W2,      // [32]
    const float* __restrict__ b2,      // [1]
    float* __restrict__ out,           // [CASC, NCELLS]
    double* __restrict__ sum_ws)
{
    // wq[j] = {W1[j], W1[32+j], W1[64+j], b1[j]};  w2s[j] = W2[j]
    __shared__ float4 wq[32];
    __shared__ float w2s[32];
    __shared__ double sdata[4];
    if (threadIdx.x < 32) {
        const int j = threadIdx.x;
        wq[j] = make_float4(W1[j], W1[32 + j], W1[64 + j], b1[j]);
        w2s[j] = W2[j];
    }
    __syncthreads();

    const float bb2 = b2[0];
    const int t8 = blockIdx.x * 256 + (int)threadIdx.x;    // 8-cell group index
    const int gidA = t8 * 2;                               // float4-group 0
    const int gidB = t8 * 2 + 1;                           // float4-group 1

    const float4* dg4 = (const float4*)dgrid;
    // group A dgrid loads
    const float4 gA_0 = dg4[(size_t)0 * (NCELLS / 4) + gidA];
    const float4 gA_1 = dg4[(size_t)1 * (NCELLS / 4) + gidA];
    const float4 gA_2 = dg4[(size_t)2 * (NCELLS / 4) + gidA];
    const float4 gA_3 = dg4[(size_t)3 * (NCELLS / 4) + gidA];
    // group B dgrid loads
    const float4 gB_0 = dg4[(size_t)0 * (NCELLS / 4) + gidB];
    const float4 gB_1 = dg4[(size_t)1 * (NCELLS / 4) + gidB];
    const float4 gB_2 = dg4[(size_t)2 * (NCELLS / 4) + gidB];
    const float4 gB_3 = dg4[(size_t)3 * (NCELLS / 4) + gidB];

    // ---- per-point coords, dwordx3 jitter loads, packed positions ----
    // G: group tag (A/B), M0: base morton of the group, K: point 0..3
#define PREP(G, M0, K) \
    const int m_##G##K = (M0) + K; \
    const unsigned x_##G##K = compact3((unsigned)m_##G##K); \
    const unsigned y_##G##K = compact3((unsigned)m_##G##K >> 1); \
    const unsigned z_##G##K = compact3((unsigned)m_##G##K >> 2); \
    const size_t jb_##G##K = ((size_t)((x_##G##K << 14) | (y_##G##K << 7) | z_##G##K)) * 3; \
    const float cx_##G##K = (float)x_##G##K, cy_##G##K = (float)y_##G##K, cz_##G##K = (float)z_##G##K; \
    const f3v ja_##G##K = load3(jit + jb_##G##K); \
    const f3v jb2_##G##K = load3(jit + (size_t)NCELLS * 3 + jb_##G##K); \
    const f3v jc_##G##K = load3(jit + (size_t)NCELLS * 6 + jb_##G##K); \
    const f3v jd_##G##K = load3(jit + (size_t)NCELLS * 9 + jb_##G##K); \
    const f32x2 pxA_##G##K = { ((cx_##G##K + ja_##G##K.x) * (1.0f / 128.0f) - 0.5f) * 1.0f, \
                               ((cx_##G##K + jb2_##G##K.x) * (1.0f / 128.0f) - 0.5f) * 2.0f }; \
    const f32x2 pxB_##G##K = { ((cx_##G##K + jc_##G##K.x) * (1.0f / 128.0f) - 0.5f) * 4.0f, \
                               ((cx_##G##K + jd_##G##K.x) * (1.0f / 128.0f) - 0.5f) * 8.0f }; \
    const f32x2 pyA_##G##K = { ((cy_##G##K + ja_##G##K.y) * (1.0f / 128.0f) - 0.5f) * 1.0f, \
                               ((cy_##G##K + jb2_##G##K.y) * (1.0f / 128.0f) - 0.5f) * 2.0f }; \
    const f32x2 pyB_##G##K = { ((cy_##G##K + jc_##G##K.y) * (1.0f / 128.0f) - 0.5f) * 4.0f, \
                               ((cy_##G##K + jd_##G##K.y) * (1.0f / 128.0f) - 0.5f) * 8.0f }; \
    const f32x2 pzA_##G##K = { ((cz_##G##K + ja_##G##K.z) * (1.0f / 128.0f) - 0.5f) * 1.0f, \
                               ((cz_##G##K + jb2_##G##K.z) * (1.0f / 128.0f) - 0.5f) * 2.0f }; \
    const f32x2 pzB_##G##K = { ((cz_##G##K + jc_##G##K.z) * (1.0f / 128.0f) - 0.5f) * 4.0f, \
                               ((cz_##G##K + jd_##G##K.z) * (1.0f / 128.0f) - 0.5f) * 8.0f }; \
    f32x2 accA_##G##K = {bb2, bb2}, accB_##G##K = {bb2, bb2};

    const int mA0 = gidA * 4;
    const int mB0 = gidB * 4;
    PREP(A, mA0, 0) PREP(A, mA0, 1) PREP(A, mA0, 2) PREP(A, mA0, 3)
    PREP(B, mB0, 0) PREP(B, mB0, 1) PREP(B, mB0, 2) PREP(B, mB0, 3)
#undef PREP

    const f32x2 zer = {0.0f, 0.0f};

    // ---- j-outer MLP: one weight fetch per j feeds 16 chains (32 cells) ----
#define STEP(G, K) { \
        f32x2 hA = pk_fma(pxA_##G##K, wx, wb); \
        f32x2 hB = pk_fma(pxB_##G##K, wx, wb); \
        hA = pk_fma(pyA_##G##K, wy, hA); \
        hB = pk_fma(pyB_##G##K, wy, hB); \
        hA = pk_fma(pzA_##G##K, wz, hA); \
        hB = pk_fma(pzB_##G##K, wz, hB); \
        hA = __builtin_elementwise_max(hA, zer); \
        hB = __builtin_elementwise_max(hB, zer); \
        accA_##G##K = pk_fma(hA, uu, accA_##G##K); \
        accB_##G##K = pk_fma(hB, uu, accB_##G##K); }

    #pragma unroll 4
    for (int j = 0; j < 32; ++j) {
        const float4 w = wq[j];
        const float u = w2s[j];
        const f32x2 wx = {w.x, w.x}, wy = {w.y, w.y}, wz = {w.z, w.z};
        const f32x2 wb = {w.w, w.w}, uu = {u, u};
        STEP(A, 0) STEP(A, 1) STEP(A, 2) STEP(A, 3)
        STEP(B, 0) STEP(B, 1) STEP(B, 2) STEP(B, 3)
    }
#undef STEP

    double lsum = 0.0;
    float nA0_0, nA0_1, nA0_2, nA0_3, nA1_0, nA1_1, nA1_2, nA1_3;
    float nA2_0, nA2_1, nA2_2, nA2_3, nA3_0, nA3_1, nA3_2, nA3_3;
    float nB0_0, nB0_1, nB0_2, nB0_3, nB1_0, nB1_1, nB1_2, nB1_3;
    float nB2_0, nB2_1, nB2_2, nB2_3, nB3_0, nB3_1, nB3_2, nB3_3;

#define TAIL(G, K, C) { \
    const float a0 = accA_##G##K.x; \
    const float d0 = fast_softplus(a0); \
    const float g0 = g##G##_0.C; \
    n##G##0_##K = (g0 >= 0.0f && d0 >= 0.0f) ? fmaxf(g0 * 0.95f, d0) : g0; \
    lsum += (double)n##G##0_##K; \
    const float a1 = accA_##G##K.y; \
    const float d1 = fast_softplus(a1); \
    const float g1 = g##G##_1.C; \
    n##G##1_##K = (g1 >= 0.0f && d1 >= 0.0f) ? fmaxf(g1 * 0.95f, d1) : g1; \
    lsum += (double)n##G##1_##K; \
    const float a2 = accB_##G##K.x; \
    const float d2 = fast_softplus(a2); \
    const float g2 = g##G##_2.C; \
    n##G##2_##K = (g2 >= 0.0f && d2 >= 0.0f) ? fmaxf(g2 * 0.95f, d2) : g2; \
    lsum += (double)n##G##2_##K; \
    const float a3 = accB_##G##K.y; \
    const float d3 = fast_softplus(a3); \
    const float g3 = g##G##_3.C; \
    n##G##3_##K = (g3 >= 0.0f && d3 >= 0.0f) ? fmaxf(g3 * 0.95f, d3) : g3; \
    lsum += (double)n##G##3_##K; }

    TAIL(A, 0, x) TAIL(A, 1, y) TAIL(A, 2, z) TAIL(A, 3, w)
    TAIL(B, 0, x) TAIL(B, 1, y) TAIL(B, 2, z) TAIL(B, 3, w)
#undef TAIL

    // ---- coalesced float4 stores (two dwordx4 per cascade) ----
    float4* o4 = (float4*)out;
    o4[(size_t)0 * (NCELLS / 4) + gidA] = make_float4(nA0_0, nA0_1, nA0_2, nA0_3);
    o4[(size_t)1 * (NCELLS / 4) + gidA] = make_float4(nA1_0, nA1_1, nA1_2, nA1_3);
    o4[(size_t)2 * (NCELLS / 4) + gidA] = make_float4(nA2_0, nA2_1, nA2_2, nA2_3);
    o4[(size_t)3 * (NCELLS / 4) + gidA] = make_float4(nA3_0, nA3_1, nA3_2, nA3_3);
    o4[(size_t)0 * (NCELLS / 4) + gidB] = make_float4(nB0_0, nB0_1, nB0_2, nB0_3);
    o4[(size_t)1 * (NCELLS / 4) + gidB] = make_float4(nB1_0, nB1_1, nB1_2, nB1_3);
    o4[(size_t)2 * (NCELLS / 4) + gidB] = make_float4(nB2_0, nB2_1, nB2_2, nB2_3);
    o4[(size_t)3 * (NCELLS / 4) + gidB] = make_float4(nB3_0, nB3_1, nB3_2, nB3_3);

    // wave-level f64 reduction -> 4 LDS partials -> one atomic per block
    #pragma unroll
    for (int s = 32; s > 0; s >>= 1) lsum += __shfl_down(lsum, s);
    const int wid = threadIdx.x >> 6;
    const int lane = threadIdx.x & 63;
    if (lane == 0) sdata[wid] = lsum;
    __syncthreads();
    if (threadIdx.x == 0)
        atomicAdd(sum_ws, (sdata[0] + sdata[1]) + (sdata[2] + sdata[3]));
}

// One thread per output byte. mean = sum * 2^-23 (bit-exact vs /GRID_TOTAL).
__global__ __launch_bounds__(256) void dg_bitfield(
    const float* __restrict__ grid,
    const double* __restrict__ sum_ws,
    float* __restrict__ outb,
    float* __restrict__ mean_out)
{
    const int i = blockIdx.x * 256 + threadIdx.x;
    const double mean = *sum_ws * (1.0 / (double)GRID_TOTAL);
    const float mf = (float)mean;
    if (i == 0) mean_out[0] = mf;
    const float t = fminf(mf, 2.0f);
    const float4* p = (const float4*)(grid + (size_t)i * 8);
    const float4 a = p[0];
    const float4 b = p[1];
    int v = 0;
    v |= (a.x > t) ? 1   : 0;
    v |= (a.y > t) ? 2   : 0;
    v |= (a.z > t) ? 4   : 0;
    v |= (a.w > t) ? 8   : 0;
    v |= (b.x > t) ? 16  : 0;
    v |= (b.y > t) ? 32  : 0;
    v |= (b.z > t) ? 64  : 0;
    v |= (b.w > t) ? 128 : 0;
    outb[i] = (float)v;
}

extern "C" void kernel_launch(void* const* d_in, const int* in_sizes, int n_in,
                              void* d_out, int out_size, void* d_ws, size_t ws_size,
                              hipStream_t stream) {
    const float* dgrid = (const float*)d_in[0];
    const float* jit   = (const float*)d_in[1];
    const float* W1    = (const float*)d_in[2];
    const float* b1    = (const float*)d_in[3];
    const float* W2    = (const float*)d_in[4];
    const float* b2    = (const float*)d_in[5];

    float* out = (float*)d_out;
    double* sum_ws = (double*)d_ws;

    hipMemsetAsync(d_ws, 0, 8, stream);   // zero the f64 accumulator (capture-safe)

    dg_main<<<MAIN_BLOCKS, 256, 0, stream>>>(dgrid, jit, W1, b1, W2, b2, out, sum_ws);
    dg_bitfield<<<NBYTES / 256, 256, 0, stream>>>(out, sum_ws,
                                                  out + GRID_TOTAL + 1,
                                                  out + GRID_TOTAL);
}

// Round 22
// 66.019 us; speedup vs baseline: 1.3097x; 1.3097x over previous
//
#include <hip/hip_runtime.h>

#define RES 128
#define NCELLS (RES * RES * RES)        // 2097152
#define CASC 4
#define GRID_TOTAL (CASC * NCELLS)      // 8388608 = 2^23
#define NBYTES (GRID_TOTAL / 8)         // 1048576
#define MAIN_BLOCKS (NCELLS / (256 * 4))     // 2048 (4 consecutive morton/thread)

typedef float f32x2 __attribute__((ext_vector_type(2)));

struct f3v { float x, y, z; };
__device__ __forceinline__ f3v load3(const float* __restrict__ p) {
    f3v v;
    __builtin_memcpy(&v, p, sizeof(f3v));   // -> global_load_dwordx3 (12B, 4B-aligned)
    return v;
}

// inverse of instant-ngp expand_bits: gather every 3rd bit
__device__ __forceinline__ unsigned compact3(unsigned v) {
    v &= 0x49249249u;
    v = (v | (v >> 2))  & 0xC30C30C3u;
    v = (v | (v >> 4))  & 0x0F00F00Fu;
    v = (v | (v >> 8))  & 0xFF0000FFu;
    v = (v | (v >> 16)) & 0x3FFu;
    return v;
}

__device__ __forceinline__ f32x2 pk_fma(f32x2 a, f32x2 b, f32x2 c) {
    return __builtin_elementwise_fma(a, b, c);   // v_pk_fma_f32, IEEE fma per lane
}

// fast softplus: hardware v_exp_f32 / v_log_f32 (~8 instrs vs libm's ~50).
__device__ __forceinline__ float fast_softplus(float a) {
    return fmaxf(a, 0.0f) + __logf(1.0f + __expf(-fabsf(a)));
}

// R20 structure + split-pipeline: all 16 gathers issued upfront, but the MLP
// runs as two j-loops — points {0,1} first (their compute needs only the A-half
// loads, so the B-half's L3 gather latency hides under ~640 packed fma), then
// points {2,3}. Per-cell arithmetic byte-identical to R20.
__global__ __launch_bounds__(256) void dg_main(
    const float* __restrict__ dgrid,   // [CASC, NCELLS]
    const float* __restrict__ jit,     // [CASC, NCELLS, 3]
    const float* __restrict__ W1,      // [3,32]
    const float* __restrict__ b1,      // [32]
    const float* __restrict__ W2,      // [32]
    const float* __restrict__ b2,      // [1]
    float* __restrict__ out,           // [CASC, NCELLS]
    double* __restrict__ sum_ws)
{
    // wq[j] = {W1[j], W1[32+j], W1[64+j], b1[j]};  w2s[j] = W2[j]
    __shared__ float4 wq[32];
    __shared__ float w2s[32];
    __shared__ double sdata[4];
    if (threadIdx.x < 32) {
        const int j = threadIdx.x;
        wq[j] = make_float4(W1[j], W1[32 + j], W1[64 + j], b1[j]);
        w2s[j] = W2[j];
    }
    __syncthreads();

    const float bb2 = b2[0];
    const int gid = blockIdx.x * 256 + (int)threadIdx.x;   // float4-group index
    const int m0 = gid * 4;

    // ---- coalesced float4 dgrid loads (one dwordx4 per cascade) ----
    const float4* dg4 = (const float4*)dgrid;
    const float4 g4_0 = dg4[(size_t)0 * (NCELLS / 4) + gid];
    const float4 g4_1 = dg4[(size_t)1 * (NCELLS / 4) + gid];
    const float4 g4_2 = dg4[(size_t)2 * (NCELLS / 4) + gid];
    const float4 g4_3 = dg4[(size_t)3 * (NCELLS / 4) + gid];

    // ---- issue ALL jitter loads upfront (named registers; 16 dwordx3) ----
#define JLOAD(K) \
    const int m_##K = m0 + K; \
    const unsigned x_##K = compact3((unsigned)m_##K); \
    const unsigned y_##K = compact3((unsigned)m_##K >> 1); \
    const unsigned z_##K = compact3((unsigned)m_##K >> 2); \
    const size_t jb_##K = ((size_t)((x_##K << 14) | (y_##K << 7) | z_##K)) * 3; \
    const float cx_##K = (float)x_##K, cy_##K = (float)y_##K, cz_##K = (float)z_##K; \
    const f3v ja_##K = load3(jit + jb_##K);                        /* cascade 0 */ \
    const f3v jb2_##K = load3(jit + (size_t)NCELLS * 3 + jb_##K);  /* cascade 1 */ \
    const f3v jc_##K = load3(jit + (size_t)NCELLS * 6 + jb_##K);   /* cascade 2 */ \
    const f3v jd_##K = load3(jit + (size_t)NCELLS * 9 + jb_##K);   /* cascade 3 */

    JLOAD(0) JLOAD(1) JLOAD(2) JLOAD(3)
#undef JLOAD

    // ---- positions for a point (identical op order to reference) ----
#define POS(K) \
    const f32x2 pxA_##K = { ((cx_##K + ja_##K.x) * (1.0f / 128.0f) - 0.5f) * 1.0f, \
                            ((cx_##K + jb2_##K.x) * (1.0f / 128.0f) - 0.5f) * 2.0f }; \
    const f32x2 pxB_##K = { ((cx_##K + jc_##K.x) * (1.0f / 128.0f) - 0.5f) * 4.0f, \
                            ((cx_##K + jd_##K.x) * (1.0f / 128.0f) - 0.5f) * 8.0f }; \
    const f32x2 pyA_##K = { ((cy_##K + ja_##K.y) * (1.0f / 128.0f) - 0.5f) * 1.0f, \
                            ((cy_##K + jb2_##K.y) * (1.0f / 128.0f) - 0.5f) * 2.0f }; \
    const f32x2 pyB_##K = { ((cy_##K + jc_##K.y) * (1.0f / 128.0f) - 0.5f) * 4.0f, \
                            ((cy_##K + jd_##K.y) * (1.0f / 128.0f) - 0.5f) * 8.0f }; \
    const f32x2 pzA_##K = { ((cz_##K + ja_##K.z) * (1.0f / 128.0f) - 0.5f) * 1.0f, \
                            ((cz_##K + jb2_##K.z) * (1.0f / 128.0f) - 0.5f) * 2.0f }; \
    const f32x2 pzB_##K = { ((cz_##K + jc_##K.z) * (1.0f / 128.0f) - 0.5f) * 4.0f, \
                            ((cz_##K + jd_##K.z) * (1.0f / 128.0f) - 0.5f) * 8.0f }; \
    f32x2 accA_##K = {bb2, bb2}, accB_##K = {bb2, bb2};

#define STEP(K) { \
        f32x2 hA = pk_fma(pxA_##K, wx, wb); \
        f32x2 hB = pk_fma(pxB_##K, wx, wb); \
        hA = pk_fma(pyA_##K, wy, hA); \
        hB = pk_fma(pyB_##K, wy, hB); \
        hA = pk_fma(pzA_##K, wz, hA); \
        hB = pk_fma(pzB_##K, wz, hB); \
        hA = __builtin_elementwise_max(hA, zer); \
        hB = __builtin_elementwise_max(hB, zer); \
        accA_##K = pk_fma(hA, uu, accA_##K); \
        accB_##K = pk_fma(hB, uu, accB_##K); }

    const f32x2 zer = {0.0f, 0.0f};

    // ---- phase A: points {0,1} — only waits on the A-half loads ----
    POS(0) POS(1)
    #pragma unroll 4
    for (int j = 0; j < 32; ++j) {
        const float4 w = wq[j];
        const float u = w2s[j];
        const f32x2 wx = {w.x, w.x}, wy = {w.y, w.y}, wz = {w.z, w.z};
        const f32x2 wb = {w.w, w.w}, uu = {u, u};
        STEP(0) STEP(1)
    }

    // ---- phase B: points {2,3} — their loads hid under phase A's fma ----
    POS(2) POS(3)
    #pragma unroll 4
    for (int j = 0; j < 32; ++j) {
        const float4 w = wq[j];
        const float u = w2s[j];
        const f32x2 wx = {w.x, w.x}, wy = {w.y, w.y}, wz = {w.z, w.z};
        const f32x2 wb = {w.w, w.w}, uu = {u, u};
        STEP(2) STEP(3)
    }
#undef STEP
#undef POS

    double lsum = 0.0;
    float n0_0, n0_1, n0_2, n0_3;   // results: n<level>_<k>
    float n1_0, n1_1, n1_2, n1_3;
    float n2_0, n2_1, n2_2, n2_3;
    float n3_0, n3_1, n3_2, n3_3;

#define TAIL(K, C) { \
    const float a0 = accA_##K.x; \
    const float d0 = fast_softplus(a0); \
    const float g0 = g4_0.C; \
    n0_##K = (g0 >= 0.0f && d0 >= 0.0f) ? fmaxf(g0 * 0.95f, d0) : g0; \
    lsum += (double)n0_##K; \
    const float a1 = accA_##K.y; \
    const float d1 = fast_softplus(a1); \
    const float g1 = g4_1.C; \
    n1_##K = (g1 >= 0.0f && d1 >= 0.0f) ? fmaxf(g1 * 0.95f, d1) : g1; \
    lsum += (double)n1_##K; \
    const float a2 = accB_##K.x; \
    const float d2 = fast_softplus(a2); \
    const float g2 = g4_2.C; \
    n2_##K = (g2 >= 0.0f && d2 >= 0.0f) ? fmaxf(g2 * 0.95f, d2) : g2; \
    lsum += (double)n2_##K; \
    const float a3 = accB_##K.y; \
    const float d3 = fast_softplus(a3); \
    const float g3 = g4_3.C; \
    n3_##K = (g3 >= 0.0f && d3 >= 0.0f) ? fmaxf(g3 * 0.95f, d3) : g3; \
    lsum += (double)n3_##K; }

    TAIL(0, x) TAIL(1, y) TAIL(2, z) TAIL(3, w)
#undef TAIL

    // ---- coalesced float4 stores (one dwordx4 per cascade) ----
    float4* o4 = (float4*)out;
    o4[(size_t)0 * (NCELLS / 4) + gid] = make_float4(n0_0, n0_1, n0_2, n0_3);
    o4[(size_t)1 * (NCELLS / 4) + gid] = make_float4(n1_0, n1_1, n1_2, n1_3);
    o4[(size_t)2 * (NCELLS / 4) + gid] = make_float4(n2_0, n2_1, n2_2, n2_3);
    o4[(size_t)3 * (NCELLS / 4) + gid] = make_float4(n3_0, n3_1, n3_2, n3_3);

    // wave-level f64 reduction -> 4 LDS partials -> one atomic per block
    #pragma unroll
    for (int s = 32; s > 0; s >>= 1) lsum += __shfl_down(lsum, s);
    const int wid = threadIdx.x >> 6;
    const int lane = threadIdx.x & 63;
    if (lane == 0) sdata[wid] = lsum;
    __syncthreads();
    if (threadIdx.x == 0)
        atomicAdd(sum_ws, (sdata[0] + sdata[1]) + (sdata[2] + sdata[3]));
}

// One thread per output byte. mean = sum * 2^-23 (bit-exact vs /GRID_TOTAL).
__global__ __launch_bounds__(256) void dg_bitfield(
    const float* __restrict__ grid,
    const double* __restrict__ sum_ws,
    float* __restrict__ outb,
    float* __restrict__ mean_out)
{
    const int i = blockIdx.x * 256 + threadIdx.x;
    const double mean = *sum_ws * (1.0 / (double)GRID_TOTAL);
    const float mf = (float)mean;
    if (i == 0) mean_out[0] = mf;
    const float t = fminf(mf, 2.0f);
    const float4* p = (const float4*)(grid + (size_t)i * 8);
    const float4 a = p[0];
    const float4 b = p[1];
    int v = 0;
    v |= (a.x > t) ? 1   : 0;
    v |= (a.y > t) ? 2   : 0;
    v |= (a.z > t) ? 4   : 0;
    v |= (a.w > t) ? 8   : 0;
    v |= (b.x > t) ? 16  : 0;
    v |= (b.y > t) ? 32  : 0;
    v |= (b.z > t) ? 64  : 0;
    v |= (b.w > t) ? 128 : 0;
    outb[i] = (float)v;
}

extern "C" void kernel_launch(void* const* d_in, const int* in_sizes, int n_in,
                              void* d_out, int out_size, void* d_ws, size_t ws_size,
                              hipStream_t stream) {
    const float* dgrid = (const float*)d_in[0];
    const float* jit   = (const float*)d_in[1];
    const float* W1    = (const float*)d_in[2];
    const float* b1    = (const float*)d_in[3];
    const float* W2    = (const float*)d_in[4];
    const float* b2    = (const float*)d_in[5];

    float* out = (float*)d_out;
    double* sum_ws = (double*)d_ws;

    hipMemsetAsync(d_ws, 0, 8, stream);   // zero the f64 accumulator (capture-safe)

    dg_main<<<MAIN_BLOCKS, 256, 0, stream>>>(dgrid, jit, W1, b1, W2, b2, out, sum_ws);
    dg_bitfield<<<NBYTES / 256, 256, 0, stream>>>(out, sum_ws,
                                                  out + GRID_TOTAL + 1,
                                                  out + GRID_TOTAL);
}

// Round 23
// 64.097 us; speedup vs baseline: 1.3490x; 1.0300x over previous
//
#include <hip/hip_runtime.h>

#define RES 128
#define NCELLS (RES * RES * RES)        // 2097152
#define CASC 4
#define GRID_TOTAL (CASC * NCELLS)      // 8388608 = 2^23
#define NBYTES (GRID_TOTAL / 8)         // 1048576
#define MAIN_BLOCKS (NCELLS / (256 * 4))     // 2048 (4 consecutive morton/thread)

typedef float f32x2 __attribute__((ext_vector_type(2)));

struct f3v { float x, y, z; };
__device__ __forceinline__ f3v load3(const float* __restrict__ p) {
    f3v v;
    __builtin_memcpy(&v, p, sizeof(f3v));   // -> global_load_dwordx3 (12B, 4B-aligned)
    return v;
}

// inverse of instant-ngp expand_bits: gather every 3rd bit
__device__ __forceinline__ unsigned compact3(unsigned v) {
    v &= 0x49249249u;
    v = (v | (v >> 2))  & 0xC30C30C3u;
    v = (v | (v >> 4))  & 0x0F00F00Fu;
    v = (v | (v >> 8))  & 0xFF0000FFu;
    v = (v | (v >> 16)) & 0x3FFu;
    return v;
}

__device__ __forceinline__ f32x2 pk_fma(f32x2 a, f32x2 b, f32x2 c) {
    return __builtin_elementwise_fma(a, b, c);   // v_pk_fma_f32, IEEE fma per lane
}

// fast softplus: hardware v_exp_f32 / v_log_f32 (~8 instrs vs libm's ~50).
// abs error ~1e-6 — well inside the pipeline's existing slack vs ref.
__device__ __forceinline__ float fast_softplus(float a) {
    return fmaxf(a, 0.0f) + __logf(1.0f + __expf(-fabsf(a)));
}

// 2048 blocks x 256 threads; thread gid handles morton m = gid*4 + {0,1,2,3}.
// Best-known structure (R20, 65.2us): dwordx3 jitter gathers, float4 dgrid/out,
// j-outer weight loop from LDS, HW-transcendental softplus. The kernel is
// bound by L3/fabric gather line-bandwidth (~5 TB/s effective) — instruction
// counts, coalescing conversion, and ILP/TLP shaping were all measured null.
__global__ __launch_bounds__(256) void dg_main(
    const float* __restrict__ dgrid,   // [CASC, NCELLS]
    const float* __restrict__ jit,     // [CASC, NCELLS, 3]
    const float* __restrict__ W1,      // [3,32]
    const float* __restrict__ b1,      // [32]
    const float* __restrict__ W2,      // [32]
    const float* __restrict__ b2,      // [1]
    float* __restrict__ out,           // [CASC, NCELLS]
    double* __restrict__ sum_ws)
{
    // wq[j] = {W1[j], W1[32+j], W1[64+j], b1[j]};  w2s[j] = W2[j]
    __shared__ float4 wq[32];
    __shared__ float w2s[32];
    __shared__ double sdata[4];
    if (threadIdx.x < 32) {
        const int j = threadIdx.x;
        wq[j] = make_float4(W1[j], W1[32 + j], W1[64 + j], b1[j]);
        w2s[j] = W2[j];
    }
    __syncthreads();

    const float bb2 = b2[0];
    const int gid = blockIdx.x * 256 + (int)threadIdx.x;   // float4-group index
    const int m0 = gid * 4;

    // ---- coalesced float4 dgrid loads (one dwordx4 per cascade) ----
    const float4* dg4 = (const float4*)dgrid;
    const float4 g4_0 = dg4[(size_t)0 * (NCELLS / 4) + gid];
    const float4 g4_1 = dg4[(size_t)1 * (NCELLS / 4) + gid];
    const float4 g4_2 = dg4[(size_t)2 * (NCELLS / 4) + gid];
    const float4 g4_3 = dg4[(size_t)3 * (NCELLS / 4) + gid];

    // ---- per-point coords, dwordx3 jitter loads, packed positions ----
#define PREP(K) \
    const int m_##K = m0 + K; \
    const unsigned x_##K = compact3((unsigned)m_##K); \
    const unsigned y_##K = compact3((unsigned)m_##K >> 1); \
    const unsigned z_##K = compact3((unsigned)m_##K >> 2); \
    const size_t jb_##K = ((size_t)((x_##K << 14) | (y_##K << 7) | z_##K)) * 3; \
    const float cx_##K = (float)x_##K, cy_##K = (float)y_##K, cz_##K = (float)z_##K; \
    const f3v ja_##K = load3(jit + jb_##K);                        /* cascade 0 */ \
    const f3v jb2_##K = load3(jit + (size_t)NCELLS * 3 + jb_##K);  /* cascade 1 */ \
    const f3v jc_##K = load3(jit + (size_t)NCELLS * 6 + jb_##K);   /* cascade 2 */ \
    const f3v jd_##K = load3(jit + (size_t)NCELLS * 9 + jb_##K);   /* cascade 3 */ \
    const f32x2 pxA_##K = { ((cx_##K + ja_##K.x) * (1.0f / 128.0f) - 0.5f) * 1.0f, \
                            ((cx_##K + jb2_##K.x) * (1.0f / 128.0f) - 0.5f) * 2.0f }; \
    const f32x2 pxB_##K = { ((cx_##K + jc_##K.x) * (1.0f / 128.0f) - 0.5f) * 4.0f, \
                            ((cx_##K + jd_##K.x) * (1.0f / 128.0f) - 0.5f) * 8.0f }; \
    const f32x2 pyA_##K = { ((cy_##K + ja_##K.y) * (1.0f / 128.0f) - 0.5f) * 1.0f, \
                            ((cy_##K + jb2_##K.y) * (1.0f / 128.0f) - 0.5f) * 2.0f }; \
    const f32x2 pyB_##K = { ((cy_##K + jc_##K.y) * (1.0f / 128.0f) - 0.5f) * 4.0f, \
                            ((cy_##K + jd_##K.y) * (1.0f / 128.0f) - 0.5f) * 8.0f }; \
    const f32x2 pzA_##K = { ((cz_##K + ja_##K.z) * (1.0f / 128.0f) - 0.5f) * 1.0f, \
                            ((cz_##K + jb2_##K.z) * (1.0f / 128.0f) - 0.5f) * 2.0f }; \
    const f32x2 pzB_##K = { ((cz_##K + jc_##K.z) * (1.0f / 128.0f) - 0.5f) * 4.0f, \
                            ((cz_##K + jd_##K.z) * (1.0f / 128.0f) - 0.5f) * 8.0f }; \
    f32x2 accA_##K = {bb2, bb2}, accB_##K = {bb2, bb2};

    PREP(0) PREP(1) PREP(2) PREP(3)
#undef PREP

    const f32x2 zer = {0.0f, 0.0f};

    // ---- j-outer MLP: one weight fetch per j feeds 8 chains (16 cells) ----
#define STEP(K) { \
        f32x2 hA = pk_fma(pxA_##K, wx, wb); \
        f32x2 hB = pk_fma(pxB_##K, wx, wb); \
        hA = pk_fma(pyA_##K, wy, hA); \
        hB = pk_fma(pyB_##K, wy, hB); \
        hA = pk_fma(pzA_##K, wz, hA); \
        hB = pk_fma(pzB_##K, wz, hB); \
        hA = __builtin_elementwise_max(hA, zer); \
        hB = __builtin_elementwise_max(hB, zer); \
        accA_##K = pk_fma(hA, uu, accA_##K); \
        accB_##K = pk_fma(hB, uu, accB_##K); }

    #pragma unroll 4
    for (int j = 0; j < 32; ++j) {
        const float4 w = wq[j];
        const float u = w2s[j];
        const f32x2 wx = {w.x, w.x}, wy = {w.y, w.y}, wz = {w.z, w.z};
        const f32x2 wb = {w.w, w.w}, uu = {u, u};
        STEP(0) STEP(1) STEP(2) STEP(3)
    }
#undef STEP

    double lsum = 0.0;
    float n0_0, n0_1, n0_2, n0_3;   // results: n<level>_<k>
    float n1_0, n1_1, n1_2, n1_3;
    float n2_0, n2_1, n2_2, n2_3;
    float n3_0, n3_1, n3_2, n3_3;

#define TAIL(K, C) { \
    const float a0 = accA_##K.x; \
    const float d0 = fast_softplus(a0); \
    const float g0 = g4_0.C; \
    n0_##K = (g0 >= 0.0f && d0 >= 0.0f) ? fmaxf(g0 * 0.95f, d0) : g0; \
    lsum += (double)n0_##K; \
    const float a1 = accA_##K.y; \
    const float d1 = fast_softplus(a1); \
    const float g1 = g4_1.C; \
    n1_##K = (g1 >= 0.0f && d1 >= 0.0f) ? fmaxf(g1 * 0.95f, d1) : g1; \
    lsum += (double)n1_##K; \
    const float a2 = accB_##K.x; \
    const float d2 = fast_softplus(a2); \
    const float g2 = g4_2.C; \
    n2_##K = (g2 >= 0.0f && d2 >= 0.0f) ? fmaxf(g2 * 0.95f, d2) : g2; \
    lsum += (double)n2_##K; \
    const float a3 = accB_##K.y; \
    const float d3 = fast_softplus(a3); \
    const float g3 = g4_3.C; \
    n3_##K = (g3 >= 0.0f && d3 >= 0.0f) ? fmaxf(g3 * 0.95f, d3) : g3; \
    lsum += (double)n3_##K; }

    TAIL(0, x) TAIL(1, y) TAIL(2, z) TAIL(3, w)
#undef TAIL

    // ---- coalesced float4 stores (one dwordx4 per cascade) ----
    float4* o4 = (float4*)out;
    o4[(size_t)0 * (NCELLS / 4) + gid] = make_float4(n0_0, n0_1, n0_2, n0_3);
    o4[(size_t)1 * (NCELLS / 4) + gid] = make_float4(n1_0, n1_1, n1_2, n1_3);
    o4[(size_t)2 * (NCELLS / 4) + gid] = make_float4(n2_0, n2_1, n2_2, n2_3);
    o4[(size_t)3 * (NCELLS / 4) + gid] = make_float4(n3_0, n3_1, n3_2, n3_3);

    // wave-level f64 reduction -> 4 LDS partials -> one atomic per block
    #pragma unroll
    for (int s = 32; s > 0; s >>= 1) lsum += __shfl_down(lsum, s);
    const int wid = threadIdx.x >> 6;
    const int lane = threadIdx.x & 63;
    if (lane == 0) sdata[wid] = lsum;
    __syncthreads();
    if (threadIdx.x == 0)
        atomicAdd(sum_ws, (sdata[0] + sdata[1]) + (sdata[2] + sdata[3]));
}

// One thread per output byte. mean = sum * 2^-23 (bit-exact vs /GRID_TOTAL).
__global__ __launch_bounds__(256) void dg_bitfield(
    const float* __restrict__ grid,
    const double* __restrict__ sum_ws,
    float* __restrict__ outb,
    float* __restrict__ mean_out)
{
    const int i = blockIdx.x * 256 + threadIdx.x;
    const double mean = *sum_ws * (1.0 / (double)GRID_TOTAL);
    const float mf = (float)mean;
    if (i == 0) mean_out[0] = mf;
    const float t = fminf(mf, 2.0f);
    const float4* p = (const float4*)(grid + (size_t)i * 8);
    const float4 a = p[0];
    const float4 b = p[1];
    int v = 0;
    v |= (a.x > t) ? 1   : 0;
    v |= (a.y > t) ? 2   : 0;
    v |= (a.z > t) ? 4   : 0;
    v |= (a.w > t) ? 8   : 0;
    v |= (b.x > t) ? 16  : 0;
    v |= (b.y > t) ? 32  : 0;
    v |= (b.z > t) ? 64  : 0;
    v |= (b.w > t) ? 128 : 0;
    outb[i] = (float)v;
}

extern "C" void kernel_launch(void* const* d_in, const int* in_sizes, int n_in,
                              void* d_out, int out_size, void* d_ws, size_t ws_size,
                              hipStream_t stream) {
    const float* dgrid = (const float*)d_in[0];
    const float* jit   = (const float*)d_in[1];
    const float* W1    = (const float*)d_in[2];
    const float* b1    = (const float*)d_in[3];
    const float* W2    = (const float*)d_in[4];
    const float* b2    = (const float*)d_in[5];

    float* out = (float*)d_out;
    double* sum_ws = (double*)d_ws;

    hipMemsetAsync(d_ws, 0, 8, stream);   // zero the f64 accumulator (capture-safe)

    dg_main<<<MAIN_BLOCKS, 256, 0, stream>>>(dgrid, jit, W1, b1, W2, b2, out, sum_ws);
    dg_bitfield<<<NBYTES / 256, 256, 0, stream>>>(out, sum_ws,
                                                  out + GRID_TOTAL + 1,
                                                  out + GRID_TOTAL);
}